// Round 18
// baseline (109.117 us; speedup 1.0000x reference)
//
#include <hip/hip_runtime.h>
#include <math.h>

// Geometry
#define NN   4
#define CI   64
#define DI   16
#define HI   56
#define WI   56
#define CO   128
#define DO_  14
#define HO   54
#define WO   54
#define TAPS 27
#define SPI  (DI*HI*WI)               // 50176 input spatial per n
#define SP   (DO_*HO*WO)              // 40824 output spatial per n
#define M_TOT (NN*SP)                 // 163296
#define WQ_BYTES (CO*TAPS*CI)         // 221184
#define XQ_BYTES ((size_t)NN*SPI*CI)  // 12845056
#define SLICE_B 24576                 // 3 taps * 8 cofrag * 4 kg * 256B

typedef int i32x4 __attribute__((ext_vector_type(4)));

// weight [Co][Ci][3][3][3] fp32 -> wq [tap][cofrag][kg][co16][ci16] int8
__global__ void quant_weight(const float* __restrict__ w, signed char* __restrict__ wq) {
    int i = blockIdx.x * 256 + threadIdx.x;
    if (i >= CO * TAPS * CI) return;
    int c  = i & 63;
    int t  = (i >> 6) % TAPS;
    int co = i / (TAPS * CI);
    float v = w[(co * CI + c) * TAPS + t];
    float q = rintf(v / 0.05f);               // RNE, IEEE div to match np
    q = fminf(fmaxf(q, -128.f), 127.f);
    int cfr = co >> 4, cl = co & 15, kg = c >> 4, ci = c & 15;
    wq[(((t * 8 + cfr) * 4 + kg) << 8) + (cl << 4) + ci] = (signed char)(int)q;
}

// input [N][Ci][D][H][W] fp32 -> xq [N][D][H][W][Ci] int8 (value xq-128)
// v3: thread = 4 spatial x 16 channels; 784 blocks; coalesced 1KB/wave stores.
__launch_bounds__(256)
__global__ void quant_input(const float* __restrict__ x, signed char* __restrict__ xq) {
    int t = blockIdx.x * 256 + threadIdx.x;       // 784*256 = 200704 exact
    int crange = t & 3;                           // which 16-c group
    int u = t >> 2;                               // 4-spatial unit, 0..50175
    int n = u / (SPI / 4);
    int spl = (u - n * (SPI / 4)) * 4;
    const float* src = x + (size_t)n * CI * SPI + (size_t)crange * 16 * SPI + spl;
    union { signed char b[4][16]; i32x4 v[4]; } pk;
#pragma unroll
    for (int i = 0; i < 16; ++i) {
        float4 v4 = *(const float4*)(src + (size_t)i * SPI);
#pragma unroll
        for (int j = 0; j < 4; ++j) {
            float v = (&v4.x)[j];
            float q = rintf(v / 0.05f) + 128.f;
            q = fminf(fmaxf(q, 0.f), 255.f);
            pk.b[j][i] = (signed char)((int)q - 128);
        }
    }
    signed char* dst = xq + ((size_t)n * SPI + spl) * 64 + crange * 16;
#pragma unroll
    for (int j = 0; j < 4; ++j)
        *(i32x4*)(dst + j * 64) = pk.v[j];
}

// Implicit GEMM, CO-SPLIT waves: block = 64m x 128co, wave = 64m x 32co
// (its own 2 cofrags). Per slice per wave: 6 ds_read_b128 + 24 MFMA ->
// LDS-pipe demand drops 2x below the MFMA floor. All 4 waves load the same
// X rows (slice window ~12KB -> L1 serves the 3 duplicates). Keeps: phase-
// staggered tap ring, X one-slice-ahead ping-pong prefetch, single
// top-of-slice barrier, W double-buffer 48KB, bijective XCD swizzle.
__launch_bounds__(256, 3)
__global__ void conv_mfma(const signed char* __restrict__ xq,
                          const signed char* __restrict__ wq,
                          const float* __restrict__ bias,
                          float* __restrict__ out) {
    __shared__ signed char lds[2][SLICE_B];       // 49152 B
    const int tid  = threadIdx.x;
    const int lane = tid & 63;
    const int wave = tid >> 6;
    const int l16  = lane & 15;
    const int kg   = lane >> 4;

    // bijective XCD swizzle (m204); nwg = 2552 = 8*319 exactly
    int bid = blockIdx.x;
    {
        const int nwg = gridDim.x, q = nwg >> 3, r = nwg & 7;
        const int xcd = bid & 7, idx = bid >> 3;
        bid = (xcd < r ? xcd * (q + 1) : r * (q + 1) + (xcd - r) * q) + idx;
    }

    const int m_base = bid * 64;            // block-wide m range (shared by waves)
    const int s0 = (bid * 2) % 9;           // per-block tap-ring phase offset

    // X row base per m-frag (4 frags of 16 m, same for all waves -> L1 reuse)
    const signed char* xrow[4];
    bool vf[4];
#pragma unroll
    for (int f = 0; f < 4; ++f) {
        int fb = m_base + f * 16;
        vf[f] = fb < M_TOT;
        int m = vf[f] ? (fb + l16) : 0;
        int n = m / SP;
        int rem = m - n * SP;
        int d = rem / (HO * WO);
        int r2 = rem - d * (HO * WO);
        int h = r2 / WO;
        int w = r2 - h * WO;
        xrow[f] = xq + (size_t)(((n * DI + d) * HI + h) * WI + w) * CI + kg * 16;
    }

    // staging: 24576B linear, 6 x 16B per thread (256 threads), ring slice rs
    auto STAGE = [&](int rs, int buf) {
        const signed char* src = wq + rs * SLICE_B;
        signed char* dst = (signed char*)lds[buf];
#pragma unroll
        for (int i = 0; i < 6; ++i) {
            __builtin_amdgcn_global_load_lds(
                (const __attribute__((address_space(1))) void*)(src + i * 4096 + tid * 16),
                (__attribute__((address_space(3))) void*)(dst + i * 4096 + tid * 16),
                16, 0, 0);
        }
    };
    // all 12 X loads for ring slice rs (4 frags x 3 kw)
    auto LOADX = [&](int rs, i32x4 xf[4][3]) {
        const int kd = rs / 3, kh = rs % 3;
        const int xoff = ((kd * HI + kh) * WI) * CI;
#pragma unroll
        for (int f = 0; f < 4; ++f)
#pragma unroll
            for (int k = 0; k < 3; ++k)
                xf[f][k] = *(const i32x4*)(xrow[f] + xoff + k * CI);
    };

    i32x4 acc[4][2];
#pragma unroll
    for (int f = 0; f < 4; ++f)
#pragma unroll
        for (int c = 0; c < 2; ++c)
            acc[f][c] = (i32x4){0, 0, 0, 0};

    i32x4 xa[4][3], xb[4][3];

    STAGE(s0, 0);                            // first ring slice into buf 0
    LOADX(s0, xa);                           // X for first slice

#pragma unroll
    for (int s = 0; s < 9; ++s) {
        const int rs = (s + s0) % 9;         // ring slice index
        __syncthreads();   // drains vmcnt (stage(s)+X(s) landed); syncs waves.
                           // Also proves all waves finished slice s-1 reads of
                           // buf[(s+1)&1] -> safe to overwrite below.

        if (s < 8) {
            STAGE((rs + 1) % 9, (s + 1) & 1);
            LOADX((rs + 1) % 9, (s & 1) ? xa : xb);   // prefetch X for s+1
        }
        i32x4 (*xc)[3] = (s & 1) ? xb : xa;

        const signed char* buf = lds[s & 1];
#pragma unroll
        for (int kw = 0; kw < 3; ++kw) {
            i32x4 wf[2];
#pragma unroll
            for (int c = 0; c < 2; ++c)
                wf[c] = *(const i32x4*)(buf + (((kw * 8 + wave * 2 + c) * 4 + kg) << 8) + (l16 << 4));
#pragma unroll
            for (int c = 0; c < 2; ++c) {
#pragma unroll
                for (int f = 0; f < 4; ++f)
                    acc[f][c] = __builtin_amdgcn_mfma_i32_16x16x64_i8(wf[c], xc[f][kw], acc[f][c], 0, 0, 0);
            }
        }
        // no end-of-slice barrier (redundant with double buffer)
    }

    const float s2 = 0.05f * 0.05f;
#pragma unroll
    for (int f = 0; f < 4; ++f) {
        if (!vf[f]) continue;
        int m = m_base + f * 16 + l16;
        int n = m / SP;
        int sp = m - n * SP;
        float* obase = out + (size_t)n * CO * SP + sp;
#pragma unroll
        for (int c = 0; c < 2; ++c) {
#pragma unroll
            for (int r = 0; r < 4; ++r) {
                int co = wave * 32 + c * 16 + kg * 4 + r;
                float y = (float)acc[f][c][r] * s2 + bias[co];
                float q = fminf(fmaxf(rintf(y), 0.f), 255.f);
                obase[(size_t)co * SP] = q;
            }
        }
    }
}

// Fallback: direct fp32 conv with inline quantization (correct, slow).
__global__ void conv_slow(const float* __restrict__ x, const float* __restrict__ w,
                          const float* __restrict__ bias, float* __restrict__ out) {
    size_t o = (size_t)blockIdx.x * 256 + threadIdx.x;
    if (o >= (size_t)M_TOT * CO) return;
    int wo = o % WO; size_t t = o / WO;
    int ho = t % HO; t /= HO;
    int dd = t % DO_; t /= DO_;
    int co = t % CO; int n = t / CO;
    int acc = 0;
    for (int c = 0; c < CI; ++c)
        for (int kd = 0; kd < 3; ++kd)
            for (int kh = 0; kh < 3; ++kh)
                for (int kw = 0; kw < 3; ++kw) {
                    float xv = x[(((size_t)(n * CI + c) * DI + dd + kd) * HI + ho + kh) * WI + wo + kw];
                    float wv = w[((size_t)co * CI + c) * TAPS + (kd * 3 + kh) * 3 + kw];
                    int a  = (int)fminf(fmaxf(rintf(xv / 0.05f) + 128.f, 0.f), 255.f) - 128;
                    int bq = (int)fminf(fmaxf(rintf(wv / 0.05f), -128.f), 127.f);
                    acc += a * bq;
                }
    float y = (float)acc * (0.05f * 0.05f) + bias[co];
    out[o] = fminf(fmaxf(rintf(y), 0.f), 255.f);
}

extern "C" void kernel_launch(void* const* d_in, const int* in_sizes, int n_in,
                              void* d_out, int out_size, void* d_ws, size_t ws_size,
                              hipStream_t stream) {
    const float* x    = (const float*)d_in[0];
    const float* w    = (const float*)d_in[1];
    const float* bias = (const float*)d_in[2];
    float* out = (float*)d_out;

    const size_t need = (size_t)WQ_BYTES + XQ_BYTES;
    if (ws_size >= need) {
        signed char* wq8 = (signed char*)d_ws;
        signed char* xq8 = (signed char*)d_ws + WQ_BYTES;
        hipLaunchKernelGGL(quant_weight, dim3((CO * TAPS * CI + 255) / 256), dim3(256), 0, stream, w, wq8);
        hipLaunchKernelGGL(quant_input, dim3(NN * SPI / 256), dim3(256), 0, stream, x, xq8);
        hipLaunchKernelGGL(conv_mfma, dim3((M_TOT + 63) / 64), dim3(256), 0, stream,
                           xq8, wq8, bias, out);
    } else {
        const size_t tot = (size_t)M_TOT * CO;
        hipLaunchKernelGGL(conv_slow, dim3((unsigned)((tot + 255) / 256)), dim3(256), 0, stream,
                           x, w, bias, out);
    }
}

// Round 19
// 75.680 us; speedup vs baseline: 1.4418x; 1.4418x over previous
//
#include <hip/hip_runtime.h>
#include <math.h>

// Geometry
#define NN   4
#define CI   64
#define DI   16
#define HI   56
#define WI   56
#define CO   128
#define DO_  14
#define HO   54
#define WO   54
#define TAPS 27
#define SPI  (DI*HI*WI)               // 50176 input spatial per n
#define SP   (DO_*HO*WO)              // 40824 output spatial per n
#define M_TOT (NN*SP)                 // 163296
#define WQ_BYTES (CO*TAPS*CI)         // 221184
#define XQ_BYTES ((size_t)NN*SPI*CI)  // 12845056
#define TAP_B   4096                  // per-tap bytes per co-half (4 cfr * 4 kg * 256)
#define SLICE_B (3*TAP_B)             // 12288
#define HALF_B  (TAPS*TAP_B)          // 110592

typedef int i32x4 __attribute__((ext_vector_type(4)));

// weight [Co][Ci][3][3][3] fp32 -> wq [half][tap][cofrag4][kg][co16][ci16] int8
__global__ void quant_weight(const float* __restrict__ w, signed char* __restrict__ wq) {
    int i = blockIdx.x * 256 + threadIdx.x;
    if (i >= CO * TAPS * CI) return;
    int c  = i & 63;
    int t  = (i >> 6) % TAPS;
    int co = i / (TAPS * CI);
    float v = w[(co * CI + c) * TAPS + t];
    float q = rintf(v / 0.05f);               // RNE, IEEE div to match np
    q = fminf(fmaxf(q, -128.f), 127.f);
    int half = co >> 6, cfr = (co >> 4) & 3, cl = co & 15, kg = c >> 4, ci = c & 15;
    wq[((((half * TAPS + t) * 4 + cfr) * 4 + kg) << 8) + (cl << 4) + ci] = (signed char)(int)q;
}

// input [N][Ci][D][H][W] fp32 -> xq [N][D][H][W][Ci] int8 (value xq-128)
// v3: thread = 4 spatial x 16 channels; 784 blocks; coalesced 1KB/wave stores.
__launch_bounds__(256)
__global__ void quant_input(const float* __restrict__ x, signed char* __restrict__ xq) {
    int t = blockIdx.x * 256 + threadIdx.x;       // 784*256 = 200704 exact
    int crange = t & 3;                           // which 16-c group
    int u = t >> 2;                               // 4-spatial unit, 0..50175
    int n = u / (SPI / 4);
    int spl = (u - n * (SPI / 4)) * 4;
    const float* src = x + (size_t)n * CI * SPI + (size_t)crange * 16 * SPI + spl;
    union { signed char b[4][16]; i32x4 v[4]; } pk;
#pragma unroll
    for (int i = 0; i < 16; ++i) {
        float4 v4 = *(const float4*)(src + (size_t)i * SPI);
#pragma unroll
        for (int j = 0; j < 4; ++j) {
            float v = (&v4.x)[j];
            float q = rintf(v / 0.05f) + 128.f;
            q = fminf(fmaxf(q, 0.f), 255.f);
            pk.b[j][i] = (signed char)((int)q - 128);
        }
    }
    signed char* dst = xq + ((size_t)n * SPI + spl) * 64 + crange * 16;
#pragma unroll
    for (int j = 0; j < 4; ++j)
        *(i32x4*)(dst + j * 64) = pk.v[j];
}

// Implicit GEMM — R14 per-wave shape (32m, 2-frag X ping-pong, proven to fit
// registers) with CO-HALVED blocks: block = 128m x 64co, slice = 12KB,
// double-buffer 24KB LDS -> 6 blocks/CU (24 waves/CU, 2x R14). More
// independently-staggered resident blocks -> more cross-block pipe overlap.
// Keeps: phase-staggered tap ring, X one-slice-ahead prefetch, single
// top-of-slice barrier, bijective XCD swizzle.
__launch_bounds__(256, 4)
__global__ void conv_mfma(const signed char* __restrict__ xq,
                          const signed char* __restrict__ wq,
                          const float* __restrict__ bias,
                          float* __restrict__ out) {
    __shared__ signed char lds[2][SLICE_B];       // 24576 B
    const int tid  = threadIdx.x;
    const int lane = tid & 63;
    const int wave = tid >> 6;
    const int l16  = lane & 15;
    const int kg   = lane >> 4;
    const int half = blockIdx.y;

    // bijective XCD swizzle (m204)
    int bid = blockIdx.x;
    {
        const int nwg = gridDim.x, q = nwg >> 3, r = nwg & 7;
        const int xcd = bid & 7, idx = bid >> 3;
        bid = (xcd < r ? xcd * (q + 1) : r * (q + 1) + (xcd - r) * q) + idx;
    }

    int m_base = bid * 128 + wave * 32;
    const bool valid = m_base < M_TOT;
    if (!valid) m_base = 0;                 // stay alive for staging/barriers

    const int s0 = (bid * 2 + half * 3) % 9;      // per-block tap-ring phase

    // X row base per m-frag (2 frags of 16 m)
    const signed char* xrow[2];
#pragma unroll
    for (int f = 0; f < 2; ++f) {
        int m = m_base + f * 16 + l16;
        int n = m / SP;
        int rem = m - n * SP;
        int d = rem / (HO * WO);
        int r2 = rem - d * (HO * WO);
        int h = r2 / WO;
        int w = r2 - h * WO;
        xrow[f] = xq + (size_t)(((n * DI + d) * HI + h) * WI + w) * CI + kg * 16;
    }

    // staging: 12288B linear, 3 x 16B per thread (256 threads), ring slice rs
    const signed char* wbase = wq + (size_t)half * HALF_B;
    auto STAGE = [&](int rs, int buf) {
        const signed char* src = wbase + rs * SLICE_B;
        signed char* dst = (signed char*)lds[buf];
#pragma unroll
        for (int i = 0; i < 3; ++i) {
            __builtin_amdgcn_global_load_lds(
                (const __attribute__((address_space(1))) void*)(src + i * 4096 + tid * 16),
                (__attribute__((address_space(3))) void*)(dst + i * 4096 + tid * 16),
                16, 0, 0);
        }
    };
    // all 6 X loads for ring slice rs (2 frags x 3 kw)
    auto LOADX = [&](int rs, i32x4 xf[2][3]) {
        const int kd = rs / 3, kh = rs % 3;
        const int xoff = ((kd * HI + kh) * WI) * CI;
#pragma unroll
        for (int f = 0; f < 2; ++f)
#pragma unroll
            for (int k = 0; k < 3; ++k)
                xf[f][k] = *(const i32x4*)(xrow[f] + xoff + k * CI);
    };

    i32x4 acc[2][4];
#pragma unroll
    for (int f = 0; f < 2; ++f)
#pragma unroll
        for (int c = 0; c < 4; ++c)
            acc[f][c] = (i32x4){0, 0, 0, 0};

    i32x4 xa[2][3], xb[2][3];

    STAGE(s0, 0);                            // first ring slice into buf 0
    LOADX(s0, xa);                           // X for first slice

#pragma unroll
    for (int s = 0; s < 9; ++s) {
        const int rs = (s + s0) % 9;         // ring slice index
        __syncthreads();   // drains vmcnt (stage(s)+X(s) landed); syncs waves.
                           // Also proves all waves finished slice s-1 reads of
                           // buf[(s+1)&1] -> safe to overwrite below.

        if (s < 8) {
            STAGE((rs + 1) % 9, (s + 1) & 1);
            LOADX((rs + 1) % 9, (s & 1) ? xa : xb);   // prefetch X for s+1
        }
        i32x4 (*xc)[3] = (s & 1) ? xb : xa;

        const signed char* buf = lds[s & 1];
#pragma unroll
        for (int kw = 0; kw < 3; ++kw) {
            i32x4 wf[4];
#pragma unroll
            for (int c = 0; c < 4; ++c)
                wf[c] = *(const i32x4*)(buf + (((kw * 4 + c) * 4 + kg) << 8) + (l16 << 4));
#pragma unroll
            for (int c = 0; c < 4; ++c) {
                acc[0][c] = __builtin_amdgcn_mfma_i32_16x16x64_i8(wf[c], xc[0][kw], acc[0][c], 0, 0, 0);
                acc[1][c] = __builtin_amdgcn_mfma_i32_16x16x64_i8(wf[c], xc[1][kw], acc[1][c], 0, 0, 0);
            }
        }
        // no end-of-slice barrier (redundant with double buffer)
    }

    if (!valid) return;
    const float s2 = 0.05f * 0.05f;
#pragma unroll
    for (int f = 0; f < 2; ++f) {
        int m = m_base + f * 16 + l16;
        int n = m / SP;
        int sp = m - n * SP;
        float* obase = out + (size_t)n * CO * SP + sp;
#pragma unroll
        for (int c = 0; c < 4; ++c) {
#pragma unroll
            for (int r = 0; r < 4; ++r) {
                int co = half * 64 + c * 16 + kg * 4 + r;
                float y = (float)acc[f][c][r] * s2 + bias[co];
                float q = fminf(fmaxf(rintf(y), 0.f), 255.f);
                obase[(size_t)co * SP] = q;
            }
        }
    }
}

// Fallback: direct fp32 conv with inline quantization (correct, slow).
__global__ void conv_slow(const float* __restrict__ x, const float* __restrict__ w,
                          const float* __restrict__ bias, float* __restrict__ out) {
    size_t o = (size_t)blockIdx.x * 256 + threadIdx.x;
    if (o >= (size_t)M_TOT * CO) return;
    int wo = o % WO; size_t t = o / WO;
    int ho = t % HO; t /= HO;
    int dd = t % DO_; t /= DO_;
    int co = t % CO; int n = t / CO;
    int acc = 0;
    for (int c = 0; c < CI; ++c)
        for (int kd = 0; kd < 3; ++kd)
            for (int kh = 0; kh < 3; ++kh)
                for (int kw = 0; kw < 3; ++kw) {
                    float xv = x[(((size_t)(n * CI + c) * DI + dd + kd) * HI + ho + kh) * WI + wo + kw];
                    float wv = w[((size_t)co * CI + c) * TAPS + (kd * 3 + kh) * 3 + kw];
                    int a  = (int)fminf(fmaxf(rintf(xv / 0.05f) + 128.f, 0.f), 255.f) - 128;
                    int bq = (int)fminf(fmaxf(rintf(wv / 0.05f), -128.f), 127.f);
                    acc += a * bq;
                }
    float y = (float)acc * (0.05f * 0.05f) + bias[co];
    out[o] = fminf(fmaxf(rintf(y), 0.f), 255.f);
}

extern "C" void kernel_launch(void* const* d_in, const int* in_sizes, int n_in,
                              void* d_out, int out_size, void* d_ws, size_t ws_size,
                              hipStream_t stream) {
    const float* x    = (const float*)d_in[0];
    const float* w    = (const float*)d_in[1];
    const float* bias = (const float*)d_in[2];
    float* out = (float*)d_out;

    const size_t need = (size_t)WQ_BYTES + XQ_BYTES;
    if (ws_size >= need) {
        signed char* wq8 = (signed char*)d_ws;
        signed char* xq8 = (signed char*)d_ws + WQ_BYTES;
        hipLaunchKernelGGL(quant_weight, dim3((CO * TAPS * CI + 255) / 256), dim3(256), 0, stream, w, wq8);
        hipLaunchKernelGGL(quant_input, dim3(NN * SPI / 256), dim3(256), 0, stream, x, xq8);
        hipLaunchKernelGGL(conv_mfma, dim3((M_TOT + 127) / 128, 2), dim3(256), 0, stream,
                           xq8, wq8, bias, out);
    } else {
        const size_t tot = (size_t)M_TOT * CO;
        hipLaunchKernelGGL(conv_slow, dim3((unsigned)((tot + 255) / 256)), dim3(256), 0, stream,
                           x, w, bias, out);
    }
}

// Round 20
// 62.941 us; speedup vs baseline: 1.7336x; 1.2024x over previous
//
#include <hip/hip_runtime.h>
#include <math.h>

// Geometry
#define NN   4
#define CI   64
#define DI   16
#define HI   56
#define WI   56
#define CO   128
#define DO_  14
#define HO   54
#define WO   54
#define TAPS 27
#define SPI  (DI*HI*WI)               // 50176 input spatial per n
#define SP   (DO_*HO*WO)              // 40824 output spatial per n
#define M_TOT (NN*SP)                 // 163296
#define WQ_BYTES (CO*TAPS*CI)         // 221184
#define XQ_BYTES ((size_t)NN*SPI*CI)  // 12845056
#define SLICE_B 24576                 // 3 taps * 8 cofrag * 4 kg * 256B

typedef int i32x4 __attribute__((ext_vector_type(4)));

// weight [Co][Ci][3][3][3] fp32 -> wq [tap][cofrag][kg][co16][ci16] int8
__global__ void quant_weight(const float* __restrict__ w, signed char* __restrict__ wq) {
    int i = blockIdx.x * 256 + threadIdx.x;
    if (i >= CO * TAPS * CI) return;
    int c  = i & 63;
    int t  = (i >> 6) % TAPS;
    int co = i / (TAPS * CI);
    float v = w[(co * CI + c) * TAPS + t];
    float q = rintf(v / 0.05f);               // RNE, IEEE div to match np
    q = fminf(fmaxf(q, -128.f), 127.f);
    int cfr = co >> 4, cl = co & 15, kg = c >> 4, ci = c & 15;
    wq[(((t * 8 + cfr) * 4 + kg) << 8) + (cl << 4) + ci] = (signed char)(int)q;
}

// input [N][Ci][D][H][W] fp32 -> xq [N][D][H][W][Ci] int8 (value xq-128)
// v3: thread = 4 spatial x 16 channels; 784 blocks; coalesced 1KB/wave stores.
__launch_bounds__(256)
__global__ void quant_input(const float* __restrict__ x, signed char* __restrict__ xq) {
    int t = blockIdx.x * 256 + threadIdx.x;       // 784*256 = 200704 exact
    int crange = t & 3;                           // which 16-c group
    int u = t >> 2;                               // 4-spatial unit, 0..50175
    int n = u / (SPI / 4);
    int spl = (u - n * (SPI / 4)) * 4;
    const float* src = x + (size_t)n * CI * SPI + (size_t)crange * 16 * SPI + spl;
    union { signed char b[4][16]; i32x4 v[4]; } pk;
#pragma unroll
    for (int i = 0; i < 16; ++i) {
        float4 v4 = *(const float4*)(src + (size_t)i * SPI);
#pragma unroll
        for (int j = 0; j < 4; ++j) {
            float v = (&v4.x)[j];
            float q = rintf(v / 0.05f) + 128.f;
            q = fminf(fmaxf(q, 0.f), 255.f);
            pk.b[j][i] = (signed char)((int)q - 128);
        }
    }
    signed char* dst = xq + ((size_t)n * SPI + spl) * 64 + crange * 16;
#pragma unroll
    for (int j = 0; j < 4; ++j)
        *(i32x4*)(dst + j * 64) = pk.v[j];
}

// Implicit GEMM — R14 winning structure (proven 53us, 68 VGPR, loads live):
// phase-staggered tap ring + X one-slice-ahead register prefetch + single
// top-of-slice barrier; 256 threads = 4 waves (32m x 128co each);
// W double-buffered 48KB; 3 blocks/CU; bijective XCD swizzle.
// R20 delta: epilogue f-innermost so the two 64B halves of each 128B output
// line are adjacent stores (write-combining -> WRITE_SIZE ~101->84MB).
__launch_bounds__(256, 3)
__global__ void conv_mfma(const signed char* __restrict__ xq,
                          const signed char* __restrict__ wq,
                          const float* __restrict__ bias,
                          float* __restrict__ out) {
    __shared__ signed char lds[2][SLICE_B];       // 49152 B
    const int tid  = threadIdx.x;
    const int lane = tid & 63;
    const int wave = tid >> 6;
    const int l16  = lane & 15;
    const int kg   = lane >> 4;

    // bijective XCD swizzle (m204)
    int bid = blockIdx.x;
    {
        const int nwg = gridDim.x, q = nwg >> 3, r = nwg & 7;
        const int xcd = bid & 7, idx = bid >> 3;
        bid = (xcd < r ? xcd * (q + 1) : r * (q + 1) + (xcd - r) * q) + idx;
    }

    int m_base = bid * 128 + wave * 32;
    const bool valid = m_base < M_TOT;
    if (!valid) m_base = 0;                 // stay alive for staging/barriers

    const int s0 = (bid * 2) % 9;           // per-block tap-ring phase offset

    // X row base per m-frag (2 frags of 16 m)
    const signed char* xrow[2];
#pragma unroll
    for (int f = 0; f < 2; ++f) {
        int m = m_base + f * 16 + l16;
        int n = m / SP;
        int rem = m - n * SP;
        int d = rem / (HO * WO);
        int r2 = rem - d * (HO * WO);
        int h = r2 / WO;
        int w = r2 - h * WO;
        xrow[f] = xq + (size_t)(((n * DI + d) * HI + h) * WI + w) * CI + kg * 16;
    }

    // staging: 24576B linear, 6 x 16B per thread (256 threads), ring slice rs
    auto STAGE = [&](int rs, int buf) {
        const signed char* src = wq + rs * SLICE_B;
        signed char* dst = (signed char*)lds[buf];
#pragma unroll
        for (int i = 0; i < 6; ++i) {
            __builtin_amdgcn_global_load_lds(
                (const __attribute__((address_space(1))) void*)(src + i * 4096 + tid * 16),
                (__attribute__((address_space(3))) void*)(dst + i * 4096 + tid * 16),
                16, 0, 0);
        }
    };
    // all 6 X loads for ring slice rs (2 frags x 3 kw)
    auto LOADX = [&](int rs, i32x4 xf[2][3]) {
        const int kd = rs / 3, kh = rs % 3;
        const int xoff = ((kd * HI + kh) * WI) * CI;
#pragma unroll
        for (int f = 0; f < 2; ++f)
#pragma unroll
            for (int k = 0; k < 3; ++k)
                xf[f][k] = *(const i32x4*)(xrow[f] + xoff + k * CI);
    };

    i32x4 acc[2][8];
#pragma unroll
    for (int f = 0; f < 2; ++f)
#pragma unroll
        for (int c = 0; c < 8; ++c)
            acc[f][c] = (i32x4){0, 0, 0, 0};

    i32x4 xa[2][3], xb[2][3];

    STAGE(s0, 0);                            // first ring slice into buf 0
    LOADX(s0, xa);                           // X for first slice

#pragma unroll
    for (int s = 0; s < 9; ++s) {
        const int rs = (s + s0) % 9;         // ring slice index
        __syncthreads();   // drains vmcnt (stage(s)+X(s) landed); syncs waves.
                           // Also proves all waves finished slice s-1 reads of
                           // buf[(s+1)&1] -> safe to overwrite below.

        if (s < 8) {
            STAGE((rs + 1) % 9, (s + 1) & 1);
            LOADX((rs + 1) % 9, (s & 1) ? xa : xb);   // prefetch X for s+1
        }
        i32x4 (*xc)[3] = (s & 1) ? xb : xa;

        const signed char* buf = lds[s & 1];
#pragma unroll
        for (int kw = 0; kw < 3; ++kw) {
            i32x4 wf[8];
#pragma unroll
            for (int c = 0; c < 8; ++c)
                wf[c] = *(const i32x4*)(buf + (((kw * 8 + c) * 4 + kg) << 8) + (l16 << 4));
#pragma unroll
            for (int c = 0; c < 8; ++c) {
                acc[0][c] = __builtin_amdgcn_mfma_i32_16x16x64_i8(wf[c], xc[0][kw], acc[0][c], 0, 0, 0);
                acc[1][c] = __builtin_amdgcn_mfma_i32_16x16x64_i8(wf[c], xc[1][kw], acc[1][c], 0, 0, 0);
            }
        }
        // no end-of-slice barrier (redundant with double buffer)
    }

    if (!valid) return;
    const float s2 = 0.05f * 0.05f;
    // per-frag output coords (m differs only by +16 between frags)
    int m0 = m_base + l16;
    int n0 = m0 / SP;
    int sp0 = m0 - n0 * SP;
    int m1 = m_base + 16 + l16;
    int n1 = m1 / SP;
    int sp1 = m1 - n1 * SP;
    float* ob0 = out + (size_t)n0 * CO * SP + sp0;
    float* ob1 = out + (size_t)n1 * CO * SP + sp1;
#pragma unroll
    for (int c = 0; c < 8; ++c) {
#pragma unroll
        for (int r = 0; r < 4; ++r) {
            int co = c * 16 + kg * 4 + r;
            float b = bias[co];
            // f=0 and f=1 back-to-back: adjacent 64B halves of one 128B line
            float y0 = (float)acc[0][c][r] * s2 + b;
            ob0[(size_t)co * SP] = fminf(fmaxf(rintf(y0), 0.f), 255.f);
            float y1 = (float)acc[1][c][r] * s2 + b;
            ob1[(size_t)co * SP] = fminf(fmaxf(rintf(y1), 0.f), 255.f);
        }
    }
}

// Fallback: direct fp32 conv with inline quantization (correct, slow).
__global__ void conv_slow(const float* __restrict__ x, const float* __restrict__ w,
                          const float* __restrict__ bias, float* __restrict__ out) {
    size_t o = (size_t)blockIdx.x * 256 + threadIdx.x;
    if (o >= (size_t)M_TOT * CO) return;
    int wo = o % WO; size_t t = o / WO;
    int ho = t % HO; t /= HO;
    int dd = t % DO_; t /= DO_;
    int co = t % CO; int n = t / CO;
    int acc = 0;
    for (int c = 0; c < CI; ++c)
        for (int kd = 0; kd < 3; ++kd)
            for (int kh = 0; kh < 3; ++kh)
                for (int kw = 0; kw < 3; ++kw) {
                    float xv = x[(((size_t)(n * CI + c) * DI + dd + kd) * HI + ho + kh) * WI + wo + kw];
                    float wv = w[((size_t)co * CI + c) * TAPS + (kd * 3 + kh) * 3 + kw];
                    int a  = (int)fminf(fmaxf(rintf(xv / 0.05f) + 128.f, 0.f), 255.f) - 128;
                    int bq = (int)fminf(fmaxf(rintf(wv / 0.05f), -128.f), 127.f);
                    acc += a * bq;
                }
    float y = (float)acc * (0.05f * 0.05f) + bias[co];
    out[o] = fminf(fmaxf(rintf(y), 0.f), 255.f);
}

extern "C" void kernel_launch(void* const* d_in, const int* in_sizes, int n_in,
                              void* d_out, int out_size, void* d_ws, size_t ws_size,
                              hipStream_t stream) {
    const float* x    = (const float*)d_in[0];
    const float* w    = (const float*)d_in[1];
    const float* bias = (const float*)d_in[2];
    float* out = (float*)d_out;

    const size_t need = (size_t)WQ_BYTES + XQ_BYTES;
    if (ws_size >= need) {
        signed char* wq8 = (signed char*)d_ws;
        signed char* xq8 = (signed char*)d_ws + WQ_BYTES;
        hipLaunchKernelGGL(quant_weight, dim3((CO * TAPS * CI + 255) / 256), dim3(256), 0, stream, w, wq8);
        hipLaunchKernelGGL(quant_input, dim3(NN * SPI / 256), dim3(256), 0, stream, x, xq8);
        hipLaunchKernelGGL(conv_mfma, dim3((M_TOT + 127) / 128), dim3(256), 0, stream,
                           xq8, wq8, bias, out);
    } else {
        const size_t tot = (size_t)M_TOT * CO;
        hipLaunchKernelGGL(conv_slow, dim3((unsigned)((tot + 255) / 256)), dim3(256), 0, stream,
                           x, w, bias, out);
    }
}

// Round 21
// 59.268 us; speedup vs baseline: 1.8411x; 1.0620x over previous
//
#include <hip/hip_runtime.h>
#include <math.h>

// Geometry
#define NN   4
#define CI   64
#define DI   16
#define HI   56
#define WI   56
#define CO   128
#define DO_  14
#define HO   54
#define WO   54
#define TAPS 27
#define SPI  (DI*HI*WI)               // 50176 input spatial per n
#define SP   (DO_*HO*WO)              // 40824 output spatial per n
#define M_TOT (NN*SP)                 // 163296
#define WQ_BYTES (CO*TAPS*CI)         // 221184
#define XQ_BYTES ((size_t)NN*SPI*CI)  // 12845056
#define SLICE_B 24576                 // 3 taps * 8 cofrag * 4 kg * 256B
#define QI_BLOCKS (NN*SPI/256)        // 784
#define QW_BLOCKS ((CO*TAPS*CI+255)/256)  // 864

typedef int i32x4 __attribute__((ext_vector_type(4)));

// Merged quantization: blocks [0,QI_BLOCKS) do input, rest do weight.
// input [N][Ci][D][H][W] fp32 -> xq [N][D][H][W][Ci] int8 (value xq-128)
// weight [Co][Ci][3][3][3] fp32 -> wq [tap][cofrag][kg][co16][ci16] int8
__launch_bounds__(256)
__global__ void quant_both(const float* __restrict__ x, const float* __restrict__ w,
                           signed char* __restrict__ xq, signed char* __restrict__ wq) {
    if (blockIdx.x < QI_BLOCKS) {
        int t = blockIdx.x * 256 + threadIdx.x;       // 784*256 = 200704 exact
        int crange = t & 3;                           // which 16-c group
        int u = t >> 2;                               // 4-spatial unit
        int n = u / (SPI / 4);
        int spl = (u - n * (SPI / 4)) * 4;
        const float* src = x + (size_t)n * CI * SPI + (size_t)crange * 16 * SPI + spl;
        union { signed char b[4][16]; i32x4 v[4]; } pk;
#pragma unroll
        for (int i = 0; i < 16; ++i) {
            float4 v4 = *(const float4*)(src + (size_t)i * SPI);
#pragma unroll
            for (int j = 0; j < 4; ++j) {
                float v = (&v4.x)[j];
                float q = rintf(v / 0.05f) + 128.f;
                q = fminf(fmaxf(q, 0.f), 255.f);
                pk.b[j][i] = (signed char)((int)q - 128);
            }
        }
        signed char* dst = xq + ((size_t)n * SPI + spl) * 64 + crange * 16;
#pragma unroll
        for (int j = 0; j < 4; ++j)
            *(i32x4*)(dst + j * 64) = pk.v[j];
    } else {
        int i = (blockIdx.x - QI_BLOCKS) * 256 + threadIdx.x;
        if (i >= CO * TAPS * CI) return;
        int c  = i & 63;
        int t  = (i >> 6) % TAPS;
        int co = i / (TAPS * CI);
        float v = w[(co * CI + c) * TAPS + t];
        float q = rintf(v / 0.05f);               // RNE, IEEE div to match np
        q = fminf(fmaxf(q, -128.f), 127.f);
        int cfr = co >> 4, cl = co & 15, kg = c >> 4, ci = c & 15;
        wq[(((t * 8 + cfr) * 4 + kg) << 8) + (cl << 4) + ci] = (signed char)(int)q;
    }
}

// Implicit GEMM — R14/R20 winning structure + in-slice W register pipeline:
// after the top-of-slice barrier: STAGE(s+1), LOADX(s+1), PREF(kw0)+PREF(kw1);
// then MFMA(kw0) | PREF(kw2) | MFMA(kw1) | MFMA(kw2) — the kw1/kw2 fragment
// reads are in flight during the previous MFMA cluster, so only kw0's ds_read
// latency is exposed per slice. All PREFs of buf[s] strictly after slice-s
// barrier (race-free, R10-verified). Keeps: phase-staggered tap ring,
// X one-slice-ahead ping-pong, single barrier, 48KB dbuf, XCD swizzle,
// f-innermost write-combined epilogue.
__launch_bounds__(256, 3)
__global__ void conv_mfma(const signed char* __restrict__ xq,
                          const signed char* __restrict__ wq,
                          const float* __restrict__ bias,
                          float* __restrict__ out) {
    __shared__ signed char lds[2][SLICE_B];       // 49152 B
    const int tid  = threadIdx.x;
    const int lane = tid & 63;
    const int wave = tid >> 6;
    const int l16  = lane & 15;
    const int kg   = lane >> 4;

    // bijective XCD swizzle (m204)
    int bid = blockIdx.x;
    {
        const int nwg = gridDim.x, q = nwg >> 3, r = nwg & 7;
        const int xcd = bid & 7, idx = bid >> 3;
        bid = (xcd < r ? xcd * (q + 1) : r * (q + 1) + (xcd - r) * q) + idx;
    }

    int m_base = bid * 128 + wave * 32;
    const bool valid = m_base < M_TOT;
    if (!valid) m_base = 0;                 // stay alive for staging/barriers

    const int s0 = (bid * 2) % 9;           // per-block tap-ring phase offset

    // X row base per m-frag (2 frags of 16 m)
    const signed char* xrow[2];
#pragma unroll
    for (int f = 0; f < 2; ++f) {
        int m = m_base + f * 16 + l16;
        int n = m / SP;
        int rem = m - n * SP;
        int d = rem / (HO * WO);
        int r2 = rem - d * (HO * WO);
        int h = r2 / WO;
        int w = r2 - h * WO;
        xrow[f] = xq + (size_t)(((n * DI + d) * HI + h) * WI + w) * CI + kg * 16;
    }

    // staging: 24576B linear, 6 x 16B per thread (256 threads), ring slice rs
    auto STAGE = [&](int rs, int buf) {
        const signed char* src = wq + rs * SLICE_B;
        signed char* dst = (signed char*)lds[buf];
#pragma unroll
        for (int i = 0; i < 6; ++i) {
            __builtin_amdgcn_global_load_lds(
                (const __attribute__((address_space(1))) void*)(src + i * 4096 + tid * 16),
                (__attribute__((address_space(3))) void*)(dst + i * 4096 + tid * 16),
                16, 0, 0);
        }
    };
    // all 6 X loads for ring slice rs (2 frags x 3 kw)
    auto LOADX = [&](int rs, i32x4 xf[2][3]) {
        const int kd = rs / 3, kh = rs % 3;
        const int xoff = ((kd * HI + kh) * WI) * CI;
#pragma unroll
        for (int f = 0; f < 2; ++f)
#pragma unroll
            for (int k = 0; k < 3; ++k)
                xf[f][k] = *(const i32x4*)(xrow[f] + xoff + k * CI);
    };
    // W-fragment read for (buffer buf, kw): 8 ds_read_b128
    auto PREF = [&](const signed char* buf, int kw, i32x4 dst[8]) {
#pragma unroll
        for (int c = 0; c < 8; ++c)
            dst[c] = *(const i32x4*)(buf + (((kw * 8 + c) * 4 + kg) << 8) + (l16 << 4));
    };

    i32x4 acc[2][8];
#pragma unroll
    for (int f = 0; f < 2; ++f)
#pragma unroll
        for (int c = 0; c < 8; ++c)
            acc[f][c] = (i32x4){0, 0, 0, 0};

    i32x4 xa[2][3], xb[2][3];

    STAGE(s0, 0);                            // first ring slice into buf 0
    LOADX(s0, xa);                           // X for first slice

#pragma unroll
    for (int s = 0; s < 9; ++s) {
        const int rs = (s + s0) % 9;         // ring slice index
        __syncthreads();   // drains vmcnt (stage(s)+X(s) landed); syncs waves.
                           // Also proves all waves finished slice s-1 reads of
                           // buf[(s+1)&1] -> safe to overwrite below.

        if (s < 8) {
            STAGE((rs + 1) % 9, (s + 1) & 1);
            LOADX((rs + 1) % 9, (s & 1) ? xa : xb);   // prefetch X for s+1
        }
        i32x4 (*xc)[3] = (s & 1) ? xb : xa;
        const signed char* buf = lds[s & 1];

        i32x4 wf0[8], wf1[8], wf2[8];
        PREF(buf, 0, wf0);
        PREF(buf, 1, wf1);

#pragma unroll
        for (int c = 0; c < 8; ++c) {
            acc[0][c] = __builtin_amdgcn_mfma_i32_16x16x64_i8(wf0[c], xc[0][0], acc[0][c], 0, 0, 0);
            acc[1][c] = __builtin_amdgcn_mfma_i32_16x16x64_i8(wf0[c], xc[1][0], acc[1][c], 0, 0, 0);
        }

        PREF(buf, 2, wf2);

#pragma unroll
        for (int c = 0; c < 8; ++c) {
            acc[0][c] = __builtin_amdgcn_mfma_i32_16x16x64_i8(wf1[c], xc[0][1], acc[0][c], 0, 0, 0);
            acc[1][c] = __builtin_amdgcn_mfma_i32_16x16x64_i8(wf1[c], xc[1][1], acc[1][c], 0, 0, 0);
        }
#pragma unroll
        for (int c = 0; c < 8; ++c) {
            acc[0][c] = __builtin_amdgcn_mfma_i32_16x16x64_i8(wf2[c], xc[0][2], acc[0][c], 0, 0, 0);
            acc[1][c] = __builtin_amdgcn_mfma_i32_16x16x64_i8(wf2[c], xc[1][2], acc[1][c], 0, 0, 0);
        }
        // no end-of-slice barrier (redundant with double buffer)
    }

    if (!valid) return;
    const float s2 = 0.05f * 0.05f;
    int m0 = m_base + l16;
    int n0 = m0 / SP;
    int sp0 = m0 - n0 * SP;
    int m1 = m_base + 16 + l16;
    int n1 = m1 / SP;
    int sp1 = m1 - n1 * SP;
    float* ob0 = out + (size_t)n0 * CO * SP + sp0;
    float* ob1 = out + (size_t)n1 * CO * SP + sp1;
#pragma unroll
    for (int c = 0; c < 8; ++c) {
#pragma unroll
        for (int r = 0; r < 4; ++r) {
            int co = c * 16 + kg * 4 + r;
            float b = bias[co];
            float y0 = (float)acc[0][c][r] * s2 + b;
            ob0[(size_t)co * SP] = fminf(fmaxf(rintf(y0), 0.f), 255.f);
            float y1 = (float)acc[1][c][r] * s2 + b;
            ob1[(size_t)co * SP] = fminf(fmaxf(rintf(y1), 0.f), 255.f);
        }
    }
}

// Fallback: direct fp32 conv with inline quantization (correct, slow).
__global__ void conv_slow(const float* __restrict__ x, const float* __restrict__ w,
                          const float* __restrict__ bias, float* __restrict__ out) {
    size_t o = (size_t)blockIdx.x * 256 + threadIdx.x;
    if (o >= (size_t)M_TOT * CO) return;
    int wo = o % WO; size_t t = o / WO;
    int ho = t % HO; t /= HO;
    int dd = t % DO_; t /= DO_;
    int co = t % CO; int n = t / CO;
    int acc = 0;
    for (int c = 0; c < CI; ++c)
        for (int kd = 0; kd < 3; ++kd)
            for (int kh = 0; kh < 3; ++kh)
                for (int kw = 0; kw < 3; ++kw) {
                    float xv = x[(((size_t)(n * CI + c) * DI + dd + kd) * HI + ho + kh) * WI + wo + kw];
                    float wv = w[((size_t)co * CI + c) * TAPS + (kd * 3 + kh) * 3 + kw];
                    int a  = (int)fminf(fmaxf(rintf(xv / 0.05f) + 128.f, 0.f), 255.f) - 128;
                    int bq = (int)fminf(fmaxf(rintf(wv / 0.05f), -128.f), 127.f);
                    acc += a * bq;
                }
    float y = (float)acc * (0.05f * 0.05f) + bias[co];
    out[o] = fminf(fmaxf(rintf(y), 0.f), 255.f);
}

extern "C" void kernel_launch(void* const* d_in, const int* in_sizes, int n_in,
                              void* d_out, int out_size, void* d_ws, size_t ws_size,
                              hipStream_t stream) {
    const float* x    = (const float*)d_in[0];
    const float* w    = (const float*)d_in[1];
    const float* bias = (const float*)d_in[2];
    float* out = (float*)d_out;

    const size_t need = (size_t)WQ_BYTES + XQ_BYTES;
    if (ws_size >= need) {
        signed char* wq8 = (signed char*)d_ws;
        signed char* xq8 = (signed char*)d_ws + WQ_BYTES;
        hipLaunchKernelGGL(quant_both, dim3(QI_BLOCKS + QW_BLOCKS), dim3(256), 0, stream,
                           x, w, xq8, wq8);
        hipLaunchKernelGGL(conv_mfma, dim3((M_TOT + 127) / 128), dim3(256), 0, stream,
                           xq8, wq8, bias, out);
    } else {
        const size_t tot = (size_t)M_TOT * CO;
        hipLaunchKernelGGL(conv_slow, dim3((unsigned)((tot + 255) / 256)), dim3(256), 0, stream,
                           x, w, bias, out);
    }
}